// Round 11
// baseline (175.460 us; speedup 1.0000x reference)
//
#include <hip/hip_runtime.h>
#include <hip/hip_bf16.h>

#define NROWS 400000
#define MSEL  100000
#define FDIM  128
#define D0 256
#define D1 256
#define D2 128

typedef __attribute__((ext_vector_type(8))) short short8;
typedef __attribute__((ext_vector_type(4))) float f32x4;
typedef __attribute__((ext_vector_type(4))) unsigned short ushort4v;
typedef __attribute__((ext_vector_type(2))) unsigned int uint2v;

__device__ __forceinline__ unsigned short f2bf(float f) {
    unsigned int u = __float_as_uint(f);
    unsigned int r = (u + 0x7fffu + ((u >> 16) & 1u)) >> 16;
    return (unsigned short)r;
}

// packed f32x2 -> bf16x2 via v_cvt_pk_bf16_f32
__device__ __forceinline__ unsigned int pk2bf(float a, float b) {
    __hip_bfloat162 h = __float22bfloat162_rn(make_float2(a, b));
    return *(unsigned int*)&h;
}

__device__ __forceinline__ float elu(float v) {
    return v > 0.f ? v : (__expf(v) - 1.f);
}

// ---------------------------------------------------------------------------
// LDS-only barrier: __syncthreads() semantics minus the vmcnt(0) drain.
// This kernel's cross-wave communication is exclusively through LDS; global
// ops (gather reads, copy loads/stores, up burst) are thread-private, so
// only lgkmcnt must drain before the barrier.  This lets the pipelined copy
// traffic stay IN FLIGHT across barriers (R9's copy serialized precisely
// because __syncthreads emits s_waitcnt vmcnt(0) before s_barrier).
// ---------------------------------------------------------------------------
__device__ __forceinline__ void ldsbar() {
    __builtin_amdgcn_sched_barrier(0);
    asm volatile("s_waitcnt lgkmcnt(0)" ::: "memory");
    __builtin_amdgcn_s_barrier();
    __builtin_amdgcn_sched_barrier(0);
}

// ---------------------------------------------------------------------------
// Repack f32 weights into bf16 B-fragment order for mfma_f32_16x16x32_bf16.
// Tile (kt,nt) is 32x16; lane l holds B[kt*32+(l>>4)*8+j][nt*16+(l&15)], 8 bf16
// contiguous per lane.  ws: W0p [0,32768) shorts, W1p [32768,98304),
// W2p [98304,131072).
// ---------------------------------------------------------------------------
__global__ void pack_weights(const float* __restrict__ W0,
                             const float* __restrict__ W1,
                             const float* __restrict__ W2,
                             short* __restrict__ out) {
    int e = blockIdx.x * 256 + threadIdx.x;
    if (e >= 131072) return;
    const float* W; int N; int base; int le;
    if (e < 32768)       { W = W0; N = 256; base = 0;     le = e; }
    else if (e < 98304)  { W = W1; N = 256; base = 32768; le = e - 32768; }
    else                 { W = W2; N = 128; base = 98304; le = e - 98304; }
    int t    = le >> 9;
    int r    = le & 511;
    int lane = r >> 3;
    int j    = r & 7;
    int ntiles = N >> 4;
    int kt = t / ntiles, nt = t % ntiles;
    int k = kt * 32 + (lane >> 4) * 8 + j;
    int n = nt * 16 + (lane & 15);
    out[base + le] = (short)f2bf(W[k * N + n]);
}

__global__ void copy_x(const float4* __restrict__ x, float4* __restrict__ out, int n4) {
    int i = blockIdx.x * blockDim.x + threadIdx.x;
    int stride = gridDim.x * blockDim.x;
    for (; i < n4; i += stride) out[i] = x[i];
}

// ---------------------------------------------------------------------------
// Inverted index of sel: head[r] -> last j with sel[j]==r, next[j] -> chain.
// ---------------------------------------------------------------------------
__global__ void init_head(int* __restrict__ head) {
    int i = blockIdx.x * 256 + threadIdx.x;
    int s = gridDim.x * 256;
    for (; i < NROWS; i += s) head[i] = -1;
}

__global__ void build_links(const int* __restrict__ sel,
                            int* __restrict__ head, int* __restrict__ next) {
    int j = blockIdx.x * 256 + threadIdx.x;
    if (j < MSEL) {
        int r = sel[j];
        next[j] = atomicExch(head + r, j);
    }
}

// ---------------------------------------------------------------------------
// Fused gather -> 3-layer ELU MLP (bf16 MFMA) -> up burst, with a pipelined
// gated copy of this block's 128-row x slice (out[row]=x[row] where head<0).
// Block = 256 thr = 4 waves, 32 selected rows; 3125 x 128 = 400000 exactly.
// Copy chunks: LOADC(c) issues 4 float4 + 4 head loads; STOREC(c) one layer
// later (counted vmcnt, no drain).  With ldsbar() the copy traffic overlaps
// the MFMA/LDS phases instead of serializing at barriers (R9's failure).
// LDS 32KB: x [0,4096) sh, h0 [4096,12288), h1 rows0-15 [12288,16384),
// rows16-31 [0,4096) (overlay; x dead after layer 0); up tile staged at
// [4096,8192) after layer 2.
// XOR swizzle shortIdx ^= (row&7)<<3 breaks ds_read_b128 bank conflicts.
// NO launch_bounds wave cap (R6: forced VGPR cap -> spill catastrophe).
// ---------------------------------------------------------------------------
template <bool SPLIT>
__global__ __launch_bounds__(256) void mlp_fused(
    const float* __restrict__ x, const int* __restrict__ sel,
    const short* __restrict__ wp,
    const float* __restrict__ b0v, const float* __restrict__ b1v,
    const float* __restrict__ b2v,
    const int* __restrict__ head,
    unsigned short* __restrict__ upOut, float* __restrict__ out) {
    __shared__ __align__(16) short lds[16384];

    const int tid  = threadIdx.x;
    const int lane = tid & 63;
    const int w    = tid >> 6;
    const int rowBase = blockIdx.x * 32;
    const int lm = lane & 15;
    const int kq = lane >> 4;
    const int sxz = (lm & 7) << 3;

    const short* W0p = wp;
    const short* W1p = wp + 32768;
    const short* W2p = wp + 98304;

    // copy-slice pointers (128 rows = 4096 float4 per block)
    const float4* xs = (const float4*)x + (size_t)blockIdx.x * 4096;
    float4* os = (float4*)out + (size_t)blockIdx.x * 4096;
    const int hbase = blockIdx.x * 128;
    float4 cc0, cc1, cc2, cc3;
    int ch0, ch1, ch2, ch3;
#define LOADC(c)  { int b_ = (c) * 1024 + tid; \
                    cc0 = xs[b_]; cc1 = xs[b_ + 256]; cc2 = xs[b_ + 512]; cc3 = xs[b_ + 768]; \
                    ch0 = head[hbase + (b_ >> 5)];        ch1 = head[hbase + ((b_ + 256) >> 5)]; \
                    ch2 = head[hbase + ((b_ + 512) >> 5)]; ch3 = head[hbase + ((b_ + 768) >> 5)]; }
#define STOREC(c) { int b_ = (c) * 1024 + tid; \
                    if (ch0 < 0) os[b_]       = cc0; if (ch1 < 0) os[b_ + 256] = cc1; \
                    if (ch2 < 0) os[b_ + 512] = cc2; if (ch3 < 0) os[b_ + 768] = cc3; }

    // gather loads first (longest pole: scattered HBM ~900cyc)
    const float4* xv = (const float4*)x;
    float4 gv[4];
    int grow[4], gseg[4];
    #pragma unroll
    for (int it = 0; it < 4; it++) {
        int i = it * 256 + tid;
        grow[it] = i >> 5; gseg[it] = i & 31;
        gv[it] = xv[(size_t)sel[rowBase + grow[it]] * 32 + gseg[it]];
    }

    // layer-0 B fragments (hide under gather)
    short8 B0[4][4];
    #pragma unroll
    for (int kt = 0; kt < 4; kt++)
        #pragma unroll
        for (int ntl = 0; ntl < 4; ntl++)
            B0[kt][ntl] = *(const short8*)(W0p + ((kt * 16 + (w * 4 + ntl)) * 512 + lane * 8));

    // chunk-0 copy loads: in flight across barrier A + layer 0
    if (SPLIT) LOADC(0);

    #pragma unroll
    for (int it = 0; it < 4; it++) {
        uint2v p = { pk2bf(gv[it].x, gv[it].y), pk2bf(gv[it].z, gv[it].w) };
        *(uint2v*)(&lds[(grow[it] * 128 + gseg[it] * 4) ^ ((grow[it] & 7) << 3)]) = p;
    }
    ldsbar();   // [A]

    const f32x4 zero4 = {0.f, 0.f, 0.f, 0.f};

    // ===== layer 0: (32x128) @ W0(128x256) =====
    {
        f32x4 acc[2][4];
        #pragma unroll
        for (int i = 0; i < 2; i++)
            #pragma unroll
            for (int j = 0; j < 4; j++) acc[i][j] = zero4;
        #pragma unroll
        for (int rt = 0; rt < 2; rt++) {
            short8 a[4];
            int rowA = rt * 16 + lm;
            #pragma unroll
            for (int kt = 0; kt < 4; kt++)
                a[kt] = *(const short8*)(&lds[(rowA * 128 + kt * 32 + kq * 8) ^ sxz]);
            #pragma unroll
            for (int ntl = 0; ntl < 4; ntl++)
                #pragma unroll
                for (int kt = 0; kt < 4; kt++)
                    acc[rt][ntl] = __builtin_amdgcn_mfma_f32_16x16x32_bf16(a[kt], B0[kt][ntl], acc[rt][ntl], 0, 0, 0);
        }
        #pragma unroll
        for (int ntl = 0; ntl < 4; ntl++) {
            int col = (w * 4 + ntl) * 16 + lm;
            float bias = b0v[col];
            #pragma unroll
            for (int rt = 0; rt < 2; rt++) {
                float v0 = elu(acc[rt][ntl][0] + bias);
                float v1 = elu(acc[rt][ntl][1] + bias);
                float v2 = elu(acc[rt][ntl][2] + bias);
                float v3 = elu(acc[rt][ntl][3] + bias);
                unsigned int u01 = pk2bf(v0, v1), u23 = pk2bf(v2, v3);
                int row = rt * 16 + kq * 4;
                lds[4096 + (((row+0) * 256 + col) ^ (((row+0) & 7) << 3))] = (short)(u01 & 0xffff);
                lds[4096 + (((row+1) * 256 + col) ^ (((row+1) & 7) << 3))] = (short)(u01 >> 16);
                lds[4096 + (((row+2) * 256 + col) ^ (((row+2) & 7) << 3))] = (short)(u23 & 0xffff);
                lds[4096 + (((row+3) * 256 + col) ^ (((row+3) & 7) << 3))] = (short)(u23 >> 16);
            }
        }
    }
    ldsbar();   // [B]

    if (SPLIT) { STOREC(0); LOADC(1); }   // chunk1 flies across layer 1

    // ===== layer 1: (32x256) @ W1(256x256), 2 col-passes =====
    // h1 overlay: rows 0-15 -> [12288,16384), rows 16-31 -> [0,4096)
    #pragma unroll
    for (int pass = 0; pass < 2; pass++) {
        short8 B1[8][2];
        #pragma unroll
        for (int kt = 0; kt < 8; kt++)
            #pragma unroll
            for (int p = 0; p < 2; p++)
                B1[kt][p] = *(const short8*)(W1p + ((kt * 16 + (w * 4 + pass * 2 + p)) * 512 + lane * 8));
        f32x4 acc[2][2];
        #pragma unroll
        for (int i = 0; i < 2; i++)
            #pragma unroll
            for (int j = 0; j < 2; j++) acc[i][j] = zero4;
        #pragma unroll
        for (int rt = 0; rt < 2; rt++) {
            short8 a[8];
            int rowA = rt * 16 + lm;
            #pragma unroll
            for (int kt = 0; kt < 8; kt++)
                a[kt] = *(const short8*)(&lds[4096 + ((rowA * 256 + kt * 32 + kq * 8) ^ sxz)]);
            #pragma unroll
            for (int p = 0; p < 2; p++)
                #pragma unroll
                for (int kt = 0; kt < 8; kt++)
                    acc[rt][p] = __builtin_amdgcn_mfma_f32_16x16x32_bf16(a[kt], B1[kt][p], acc[rt][p], 0, 0, 0);
        }
        #pragma unroll
        for (int p = 0; p < 2; p++) {
            int col = (w * 4 + pass * 2 + p) * 16 + lm;
            float bias = b1v[col];
            #pragma unroll
            for (int rt = 0; rt < 2; rt++) {
                float v0 = elu(acc[rt][p][0] + bias);
                float v1 = elu(acc[rt][p][1] + bias);
                float v2 = elu(acc[rt][p][2] + bias);
                float v3 = elu(acc[rt][p][3] + bias);
                unsigned int u01 = pk2bf(v0, v1), u23 = pk2bf(v2, v3);
                int row = rt * 16 + kq * 4;
                int hb = rt ? 0 : 12288;   // overlay base
                lds[hb + ((((row+0) & 15) * 256 + col) ^ (((row+0) & 7) << 3))] = (short)(u01 & 0xffff);
                lds[hb + ((((row+1) & 15) * 256 + col) ^ (((row+1) & 7) << 3))] = (short)(u01 >> 16);
                lds[hb + ((((row+2) & 15) * 256 + col) ^ (((row+2) & 7) << 3))] = (short)(u23 & 0xffff);
                lds[hb + ((((row+3) & 15) * 256 + col) ^ (((row+3) & 7) << 3))] = (short)(u23 >> 16);
            }
        }
        if (SPLIT && pass == 0) { STOREC(1); LOADC(2); }   // chunk2 flies across pass 1
    }
    ldsbar();   // [C]

    if (SPLIT) { STOREC(2); LOADC(3); }   // chunk3 flies across layer 2

    // ===== layer 2: (32x256) @ W2(256x128) =====
    {
        short8 B2[8][2];
        #pragma unroll
        for (int kt = 0; kt < 8; kt++)
            #pragma unroll
            for (int ntl = 0; ntl < 2; ntl++)
                B2[kt][ntl] = *(const short8*)(W2p + ((kt * 8 + (w * 2 + ntl)) * 512 + lane * 8));

        f32x4 acc[2][2];
        #pragma unroll
        for (int i = 0; i < 2; i++)
            #pragma unroll
            for (int j = 0; j < 2; j++) acc[i][j] = zero4;
        #pragma unroll
        for (int rt = 0; rt < 2; rt++) {
            short8 a[8];
            int rowA = rt * 16 + lm;
            int hb = rt ? 0 : 12288;
            #pragma unroll
            for (int kt = 0; kt < 8; kt++)
                a[kt] = *(const short8*)(&lds[hb + (((rowA & 15) * 256 + kt * 32 + kq * 8) ^ sxz)]);
            #pragma unroll
            for (int ntl = 0; ntl < 2; ntl++)
                #pragma unroll
                for (int kt = 0; kt < 8; kt++)
                    acc[rt][ntl] = __builtin_amdgcn_mfma_f32_16x16x32_bf16(a[kt], B2[kt][ntl], acc[rt][ntl], 0, 0, 0);
        }
        // epilogue 2: bias+ELU -> stage up tile in LDS (h0 region, free now)
        #pragma unroll
        for (int ntl = 0; ntl < 2; ntl++) {
            int col = (w * 2 + ntl) * 16 + lm;
            float bias = b2v[col];
            #pragma unroll
            for (int rt = 0; rt < 2; rt++)
                #pragma unroll
                for (int r = 0; r < 4; r++) {
                    int row = rt * 16 + kq * 4 + r;
                    float v = elu(acc[rt][ntl][r] + bias);
                    if (SPLIT) {
                        lds[4096 + row * 128 + col] = (short)f2bf(v);
                    } else {
                        atomicAdd(out + (size_t)sel[rowBase + row] * 128 + col, v);
                    }
                }
        }
    }
    if (SPLIT) {
        STOREC(3);
        ldsbar();   // [D]
        // coalesced up write: 32 rows x 256B = 8KB contiguous, 2 dwordx4/thr
        const short8* s8 = (const short8*)(&lds[4096]);
        short8* u8 = (short8*)(upOut + (size_t)rowBase * 128);
        u8[tid]       = s8[tid];
        u8[tid + 256] = s8[tid + 256];
    }
#undef LOADC
#undef STOREC
}

// ---------------------------------------------------------------------------
// merge: wave per TOUCHED row (head>=0): out[r] = x[r] + sum_{chain} up[j].
// Untouched rows were written by mlp_fused's gated copy.  No atomics.
// ---------------------------------------------------------------------------
__global__ __launch_bounds__(256) void merge_touched(
    const float2* __restrict__ x2, const unsigned int* __restrict__ up32,
    const int* __restrict__ head, const int* __restrict__ next,
    float2* __restrict__ out2) {
    int wid  = blockIdx.x * 4 + (threadIdx.x >> 6);
    int lane = threadIdx.x & 63;
    int wstride = gridDim.x * 4;
    for (int row = wid; row < NROWS; row += wstride) {
        int j = head[row];
        if (j < 0) continue;
        float2 v = x2[(size_t)row * 64 + lane];
        do {
            unsigned int u = up32[(size_t)j * 64 + lane];
            v.x += __uint_as_float(u << 16);
            v.y += __uint_as_float(u & 0xffff0000u);
            j = next[j];
        } while (j >= 0);
        out2[(size_t)row * 64 + lane] = v;
    }
}

extern "C" void kernel_launch(void* const* d_in, const int* in_sizes, int n_in,
                              void* d_out, int out_size, void* d_ws, size_t ws_size,
                              hipStream_t stream) {
    const float* x   = (const float*)d_in[0];
    const int*   sel = (const int*)d_in[1];
    const float* W0  = (const float*)d_in[2];
    const float* b0  = (const float*)d_in[3];
    const float* W1  = (const float*)d_in[4];
    const float* b1  = (const float*)d_in[5];
    const float* W2  = (const float*)d_in[6];
    const float* b2  = (const float*)d_in[7];
    float* out = (float*)d_out;

    char* wsb = (char*)d_ws;
    short* wp          = (short*)wsb;                                  // 262144 B
    unsigned short* up = (unsigned short*)(wsb + 262144);              // 25.6 MB
    int* head          = (int*)(wsb + 262144 + (size_t)MSEL * 256);    // 1.6 MB
    int* nxt           = head + NROWS;                                 // 0.4 MB
    const size_t need  = 262144 + (size_t)MSEL * 256 + (size_t)NROWS * 4 + (size_t)MSEL * 4;

    pack_weights<<<512, 256, 0, stream>>>(W0, W1, W2, wp);
    if (ws_size >= need) {
        init_head<<<1024, 256, 0, stream>>>(head);
        build_links<<<(MSEL + 255) / 256, 256, 0, stream>>>(sel, head, nxt);
        mlp_fused<true><<<MSEL / 32, 256, 0, stream>>>(x, sel, wp, b0, b1, b2, head, up, out);
        merge_touched<<<4096, 256, 0, stream>>>((const float2*)x, (const unsigned int*)up,
                                                head, nxt, (float2*)out);
    } else {
        copy_x<<<4096, 256, 0, stream>>>((const float4*)x, (float4*)out, NROWS * FDIM / 4);
        mlp_fused<false><<<MSEL / 32, 256, 0, stream>>>(x, sel, wp, b0, b1, b2, head, up, out);
    }
}

// Round 13
// 152.008 us; speedup vs baseline: 1.1543x; 1.1543x over previous
//
#include <hip/hip_runtime.h>
#include <hip/hip_bf16.h>

#define NROWS 400000
#define MSEL  100000
#define FDIM  128
#define D0 256
#define D1 256
#define D2 128

typedef __attribute__((ext_vector_type(8))) short short8;
typedef __attribute__((ext_vector_type(4))) float f32x4;
typedef __attribute__((ext_vector_type(2))) unsigned int uint2v;

__device__ __forceinline__ unsigned short f2bf(float f) {
    unsigned int u = __float_as_uint(f);
    unsigned int r = (u + 0x7fffu + ((u >> 16) & 1u)) >> 16;
    return (unsigned short)r;
}

// packed f32x2 -> bf16x2 via v_cvt_pk_bf16_f32 (a in low short, b in high)
__device__ __forceinline__ unsigned int pk2bf(float a, float b) {
    __hip_bfloat162 h = __float22bfloat162_rn(make_float2(a, b));
    return *(unsigned int*)&h;
}

__device__ __forceinline__ float elu(float v) {
    return v > 0.f ? v : (__expf(v) - 1.f);
}

// ---------------------------------------------------------------------------
// prep1: bid<512 -> repack f32 weights into bf16 B-fragment order
//        (tile kt,nt = 32x16; lane l holds B[kt*32+(l>>4)*8+e][nt*16+(l&15)],
//         8 bf16 contiguous per lane); bid>=512 -> head[]=-1 init.
// ws: W0p [0,32768) shorts, W1p [32768,98304), W2p [98304,131072).
// ---------------------------------------------------------------------------
__global__ void prep1(const float* __restrict__ W0,
                      const float* __restrict__ W1,
                      const float* __restrict__ W2,
                      short* __restrict__ wp, int* __restrict__ head) {
    int bid = blockIdx.x;
    if (bid < 512) {
        int e = bid * 256 + threadIdx.x;         // < 131072
        const float* W; int N; int base; int le;
        if (e < 32768)       { W = W0; N = 256; base = 0;     le = e; }
        else if (e < 98304)  { W = W1; N = 256; base = 32768; le = e - 32768; }
        else                 { W = W2; N = 128; base = 98304; le = e - 98304; }
        int t    = le >> 9;
        int r    = le & 511;
        int lane = r >> 3;
        int j    = r & 7;
        int ntiles = N >> 4;
        int kt = t / ntiles, nt = t % ntiles;
        int k = kt * 32 + (lane >> 4) * 8 + j;
        int n = nt * 16 + (lane & 15);
        wp[base + le] = (short)f2bf(W[k * N + n]);
    } else {
        int i = (bid - 512) * 256 + threadIdx.x;
        if (i < NROWS) head[i] = -1;
    }
}

// ---------------------------------------------------------------------------
// prep2: bid<391 -> build inverted index (head/next chains of sel);
//        bid>=391 -> gather x[sel[j]] -> bf16 in A-FRAGMENT ORDER into xf:
//        frag ((j>>4)*4 + kt), within it lane*8+e, lane=(j&15)+((k>>3)&3)*16,
//        k = kt*32+((k>>3)&3)*8+e.  One thread per float4: MSEL*32 = 3.2M
//        threads = 12500 blocks (R12 bug: launched only 3125 -> 75% of xf
//        stayed poisoned).  Full-occupancy scattered gather: HBM latency
//        hidden by TLP instead of stalling the low-occupancy MFMA kernel.
// ---------------------------------------------------------------------------
__global__ void prep2(const int* __restrict__ sel, const float* __restrict__ x,
                      int* __restrict__ head, int* __restrict__ next,
                      unsigned int* __restrict__ xf32) {
    int bid = blockIdx.x;
    if (bid < 391) {
        int j = bid * 256 + threadIdx.x;
        if (j < MSEL) next[j] = atomicExch(head + sel[j], j);
    } else {
        int g = (bid - 391) * 256 + threadIdx.x;   // < 3,200,000 exactly
        int j = g >> 5, seg = g & 31;
        float4 v = ((const float4*)x)[(size_t)sel[j] * 32 + seg];
        int k0 = seg * 4;
        int lane = (j & 15) + ((k0 >> 3) & 3) * 16;
        int e = k0 & 7;                            // 0 or 4
        int idx = ((((j >> 4) * 4 + (k0 >> 5)) * 512 + lane * 8 + e) >> 1);
        xf32[idx]     = pk2bf(v.x, v.y);
        xf32[idx + 1] = pk2bf(v.z, v.w);
    }
}

__global__ void copy_x(const float4* __restrict__ x, float4* __restrict__ out, int n4) {
    int i = blockIdx.x * blockDim.x + threadIdx.x;
    int stride = gridDim.x * blockDim.x;
    for (; i < n4; i += stride) out[i] = x[i];
}

// ---------------------------------------------------------------------------
// 3-layer ELU MLP (bf16 MFMA).  Block = 256 thr = 4 waves, 32 selected rows.
// Wave computes ALL rows x a 64-col slice (32-col layer 2); B-fragments
// register-resident per layer, hoisted across barriers (R10).
// SPLIT: layer-0 A-frags load DIRECT from frag-ordered xf (1KB coalesced
// dwordx4 per frag, L2/L3-hot) -> no gather phase, no x LDS region, only 3
// barriers.  up tile staged in LDS -> one coalesced 8KB burst.
// !SPLIT (fallback): inline gather into LDS + atomicAdd epilogue.
// LDS 32KB: h0 [0,8192) shorts, h1 [8192,16384).
// XOR swizzle shortIdx ^= (row&7)<<3 breaks ds_read_b128 bank conflicts.
// NO launch_bounds wave cap (R6: forced VGPR cap -> spill catastrophe).
// ---------------------------------------------------------------------------
template <bool SPLIT>
__global__ __launch_bounds__(256) void mlp_compute(
    const short* __restrict__ xf,
    const float* __restrict__ x, const int* __restrict__ sel,
    const short* __restrict__ wp,
    const float* __restrict__ b0v, const float* __restrict__ b1v,
    const float* __restrict__ b2v,
    unsigned short* __restrict__ upOut, float* __restrict__ out) {
    __shared__ __align__(16) short lds[16384];

    const int tid  = threadIdx.x;
    const int lane = tid & 63;
    const int w    = tid >> 6;
    const int rowBase = blockIdx.x * 32;
    const int lm = lane & 15;
    const int kq = lane >> 4;
    const int sxz = (lm & 7) << 3;

    const short* W0p = wp;
    const short* W1p = wp + 32768;
    const short* W2p = wp + 98304;

    // layer-0 A fragments: direct coalesced loads from frag-ordered xf
    short8 A0[2][4];
    if constexpr (SPLIT) {
        #pragma unroll
        for (int rt = 0; rt < 2; rt++)
            #pragma unroll
            for (int kt = 0; kt < 4; kt++)
                A0[rt][kt] = *(const short8*)(xf + (((size_t)blockIdx.x * 2 + rt) * 4 + kt) * 512 + lane * 8);
    }

    // layer-0 B fragments
    short8 B0[4][4];
    #pragma unroll
    for (int kt = 0; kt < 4; kt++)
        #pragma unroll
        for (int ntl = 0; ntl < 4; ntl++)
            B0[kt][ntl] = *(const short8*)(W0p + ((kt * 16 + (w * 4 + ntl)) * 512 + lane * 8));

    if constexpr (!SPLIT) {
        // fallback: inline gather into h1 region [8192,12288), swizzled
        const float4* xv = (const float4*)x;
        #pragma unroll
        for (int it = 0; it < 4; it++) {
            int i = it * 256 + tid;
            int row = i >> 5, seg = i & 31;
            float4 v = xv[(size_t)sel[rowBase + row] * 32 + seg];
            uint2v p = { pk2bf(v.x, v.y), pk2bf(v.z, v.w) };
            *(uint2v*)(&lds[8192 + ((row * 128 + seg * 4) ^ ((row & 7) << 3))]) = p;
        }
        __syncthreads();
    }

    const f32x4 zero4 = {0.f, 0.f, 0.f, 0.f};

    // ===== layer 0: (32x128) @ W0(128x256) =====
    short8 B1a[8][2];   // layer-1 pass-0 frags, hoisted across bar1
    {
        f32x4 acc[2][4];
        #pragma unroll
        for (int i = 0; i < 2; i++)
            #pragma unroll
            for (int j = 0; j < 4; j++) acc[i][j] = zero4;
        #pragma unroll
        for (int rt = 0; rt < 2; rt++) {
            short8 a[4];
            #pragma unroll
            for (int kt = 0; kt < 4; kt++) {
                if constexpr (SPLIT) a[kt] = A0[rt][kt];
                else {
                    int rowA = rt * 16 + lm;
                    a[kt] = *(const short8*)(&lds[8192 + ((rowA * 128 + kt * 32 + kq * 8) ^ sxz)]);
                }
            }
            #pragma unroll
            for (int ntl = 0; ntl < 4; ntl++)
                #pragma unroll
                for (int kt = 0; kt < 4; kt++)
                    acc[rt][ntl] = __builtin_amdgcn_mfma_f32_16x16x32_bf16(a[kt], B0[kt][ntl], acc[rt][ntl], 0, 0, 0);
        }
        // hoist: issue B1 pass-0 loads (latency hides under epilogue + bar1)
        #pragma unroll
        for (int kt = 0; kt < 8; kt++)
            #pragma unroll
            for (int p = 0; p < 2; p++)
                B1a[kt][p] = *(const short8*)(W1p + ((kt * 16 + (w * 4 + p)) * 512 + lane * 8));

        #pragma unroll
        for (int ntl = 0; ntl < 4; ntl++) {
            int col = (w * 4 + ntl) * 16 + lm;
            float bias = b0v[col];
            #pragma unroll
            for (int rt = 0; rt < 2; rt++) {
                float v0 = elu(acc[rt][ntl][0] + bias);
                float v1 = elu(acc[rt][ntl][1] + bias);
                float v2 = elu(acc[rt][ntl][2] + bias);
                float v3 = elu(acc[rt][ntl][3] + bias);
                unsigned int u01 = pk2bf(v0, v1), u23 = pk2bf(v2, v3);
                int row = rt * 16 + kq * 4;
                lds[(((row+0) * 256 + col) ^ (((row+0) & 7) << 3))] = (short)(u01 & 0xffff);
                lds[(((row+1) * 256 + col) ^ (((row+1) & 7) << 3))] = (short)(u01 >> 16);
                lds[(((row+2) * 256 + col) ^ (((row+2) & 7) << 3))] = (short)(u23 & 0xffff);
                lds[(((row+3) * 256 + col) ^ (((row+3) & 7) << 3))] = (short)(u23 >> 16);
            }
        }
    }
    __syncthreads();   // bar1

    // ===== layer 1: (32x256) @ W1(256x256), 2 col-passes =====
    short8 B2[8][2];    // layer-2 frags, hoisted across bar2
    {
        // pass 0 (B1a preloaded); issue pass-1 frags during pass 0
        short8 B1b[8][2];
        #pragma unroll
        for (int kt = 0; kt < 8; kt++)
            #pragma unroll
            for (int p = 0; p < 2; p++)
                B1b[kt][p] = *(const short8*)(W1p + ((kt * 16 + (w * 4 + 2 + p)) * 512 + lane * 8));

        f32x4 acc[2][2];
        #pragma unroll
        for (int i = 0; i < 2; i++)
            #pragma unroll
            for (int j = 0; j < 2; j++) acc[i][j] = zero4;
        #pragma unroll
        for (int rt = 0; rt < 2; rt++) {
            short8 a[8];
            int rowA = rt * 16 + lm;
            #pragma unroll
            for (int kt = 0; kt < 8; kt++)
                a[kt] = *(const short8*)(&lds[(rowA * 256 + kt * 32 + kq * 8) ^ sxz]);
            #pragma unroll
            for (int p = 0; p < 2; p++)
                #pragma unroll
                for (int kt = 0; kt < 8; kt++)
                    acc[rt][p] = __builtin_amdgcn_mfma_f32_16x16x32_bf16(a[kt], B1a[kt][p], acc[rt][p], 0, 0, 0);
        }
        #pragma unroll
        for (int p = 0; p < 2; p++) {
            int col = (w * 4 + p) * 16 + lm;
            float bias = b1v[col];
            #pragma unroll
            for (int rt = 0; rt < 2; rt++) {
                float v0 = elu(acc[rt][p][0] + bias);
                float v1 = elu(acc[rt][p][1] + bias);
                float v2 = elu(acc[rt][p][2] + bias);
                float v3 = elu(acc[rt][p][3] + bias);
                unsigned int u01 = pk2bf(v0, v1), u23 = pk2bf(v2, v3);
                int row = rt * 16 + kq * 4;
                lds[8192 + (((row+0) * 256 + col) ^ (((row+0) & 7) << 3))] = (short)(u01 & 0xffff);
                lds[8192 + (((row+1) * 256 + col) ^ (((row+1) & 7) << 3))] = (short)(u01 >> 16);
                lds[8192 + (((row+2) * 256 + col) ^ (((row+2) & 7) << 3))] = (short)(u23 & 0xffff);
                lds[8192 + (((row+3) * 256 + col) ^ (((row+3) & 7) << 3))] = (short)(u23 >> 16);
            }
        }

        // pass 1 (B1b)
        #pragma unroll
        for (int i = 0; i < 2; i++)
            #pragma unroll
            for (int j = 0; j < 2; j++) acc[i][j] = zero4;
        #pragma unroll
        for (int rt = 0; rt < 2; rt++) {
            short8 a[8];
            int rowA = rt * 16 + lm;
            #pragma unroll
            for (int kt = 0; kt < 8; kt++)
                a[kt] = *(const short8*)(&lds[(rowA * 256 + kt * 32 + kq * 8) ^ sxz]);
            #pragma unroll
            for (int p = 0; p < 2; p++)
                #pragma unroll
                for (int kt = 0; kt < 8; kt++)
                    acc[rt][p] = __builtin_amdgcn_mfma_f32_16x16x32_bf16(a[kt], B1b[kt][p], acc[rt][p], 0, 0, 0);
        }
        // hoist: issue B2 loads (latency hides under epilogue + bar2)
        #pragma unroll
        for (int kt = 0; kt < 8; kt++)
            #pragma unroll
            for (int ntl = 0; ntl < 2; ntl++)
                B2[kt][ntl] = *(const short8*)(W2p + ((kt * 8 + (w * 2 + ntl)) * 512 + lane * 8));

        #pragma unroll
        for (int p = 0; p < 2; p++) {
            int col = (w * 4 + 2 + p) * 16 + lm;
            float bias = b1v[col];
            #pragma unroll
            for (int rt = 0; rt < 2; rt++) {
                float v0 = elu(acc[rt][p][0] + bias);
                float v1 = elu(acc[rt][p][1] + bias);
                float v2 = elu(acc[rt][p][2] + bias);
                float v3 = elu(acc[rt][p][3] + bias);
                unsigned int u01 = pk2bf(v0, v1), u23 = pk2bf(v2, v3);
                int row = rt * 16 + kq * 4;
                lds[8192 + (((row+0) * 256 + col) ^ (((row+0) & 7) << 3))] = (short)(u01 & 0xffff);
                lds[8192 + (((row+1) * 256 + col) ^ (((row+1) & 7) << 3))] = (short)(u01 >> 16);
                lds[8192 + (((row+2) * 256 + col) ^ (((row+2) & 7) << 3))] = (short)(u23 & 0xffff);
                lds[8192 + (((row+3) * 256 + col) ^ (((row+3) & 7) << 3))] = (short)(u23 >> 16);
            }
        }
    }
    __syncthreads();   // bar2

    // ===== layer 2: (32x256) @ W2(256x128) =====
    {
        f32x4 acc[2][2];
        #pragma unroll
        for (int i = 0; i < 2; i++)
            #pragma unroll
            for (int j = 0; j < 2; j++) acc[i][j] = zero4;
        #pragma unroll
        for (int rt = 0; rt < 2; rt++) {
            short8 a[8];
            int rowA = rt * 16 + lm;
            #pragma unroll
            for (int kt = 0; kt < 8; kt++)
                a[kt] = *(const short8*)(&lds[8192 + ((rowA * 256 + kt * 32 + kq * 8) ^ sxz)]);
            #pragma unroll
            for (int ntl = 0; ntl < 2; ntl++)
                #pragma unroll
                for (int kt = 0; kt < 8; kt++)
                    acc[rt][ntl] = __builtin_amdgcn_mfma_f32_16x16x32_bf16(a[kt], B2[kt][ntl], acc[rt][ntl], 0, 0, 0);
        }
        // epilogue: bias+ELU -> stage up tile linear at [0,4096) (h0 dead)
        #pragma unroll
        for (int ntl = 0; ntl < 2; ntl++) {
            int col = (w * 2 + ntl) * 16 + lm;
            float bias = b2v[col];
            #pragma unroll
            for (int rt = 0; rt < 2; rt++)
                #pragma unroll
                for (int r = 0; r < 4; r++) {
                    int row = rt * 16 + kq * 4 + r;
                    float v = elu(acc[rt][ntl][r] + bias);
                    if (SPLIT) {
                        lds[row * 128 + col] = (short)f2bf(v);
                    } else {
                        atomicAdd(out + (size_t)sel[rowBase + row] * 128 + col, v);
                    }
                }
        }
    }
    if (SPLIT) {
        __syncthreads();   // bar3
        // coalesced up write: 32 rows x 256B = 8KB contiguous, 2 dwordx4/thr
        const short8* s8 = (const short8*)(&lds[0]);
        short8* u8 = (short8*)(upOut + (size_t)rowBase * 128);
        u8[tid]       = s8[tid];
        u8[tid + 256] = s8[tid + 256];
    }
}

// ---------------------------------------------------------------------------
// merge: wave per row, no atomics, no barriers (streaming at full BW).
// head==-1 -> out[r]=x[r]; else out[r] = x[r] + sum_{chain} up[j].
// ---------------------------------------------------------------------------
__global__ __launch_bounds__(256) void merge_out(
    const float2* __restrict__ x2, const unsigned int* __restrict__ up32,
    const int* __restrict__ head, const int* __restrict__ next,
    float2* __restrict__ out2) {
    int wid  = blockIdx.x * 4 + (threadIdx.x >> 6);
    int lane = threadIdx.x & 63;
    int wstride = gridDim.x * 4;
    for (int row = wid; row < NROWS; row += wstride) {
        float2 v = x2[(size_t)row * 64 + lane];
        int j = head[row];
        while (j >= 0) {
            unsigned int u = up32[(size_t)j * 64 + lane];
            v.x += __uint_as_float(u << 16);
            v.y += __uint_as_float(u & 0xffff0000u);
            j = next[j];
        }
        out2[(size_t)row * 64 + lane] = v;
    }
}

extern "C" void kernel_launch(void* const* d_in, const int* in_sizes, int n_in,
                              void* d_out, int out_size, void* d_ws, size_t ws_size,
                              hipStream_t stream) {
    const float* x   = (const float*)d_in[0];
    const int*   sel = (const int*)d_in[1];
    const float* W0  = (const float*)d_in[2];
    const float* b0  = (const float*)d_in[3];
    const float* W1  = (const float*)d_in[4];
    const float* b1  = (const float*)d_in[5];
    const float* W2  = (const float*)d_in[6];
    const float* b2  = (const float*)d_in[7];
    float* out = (float*)d_out;

    char* wsb = (char*)d_ws;
    short* wp          = (short*)wsb;                                   // 0.26 MB
    short* xf          = (short*)(wsb + 262144);                        // 25.6 MB
    unsigned short* up = (unsigned short*)(wsb + 262144 + 25600000);    // 25.6 MB
    int* head          = (int*)(wsb + 262144 + 51200000);               // 1.6 MB
    int* nxt           = head + NROWS;                                  // 0.4 MB
    const size_t need  = 262144 + 51200000 + (size_t)NROWS * 4 + (size_t)MSEL * 4;

    prep1<<<2075, 256, 0, stream>>>(W0, W1, W2, wp, head);
    if (ws_size >= need) {
        // 391 link-build blocks + 12500 gather blocks (MSEL*32 threads)
        prep2<<<12891, 256, 0, stream>>>(sel, x, head, nxt, (unsigned int*)xf);
        mlp_compute<true><<<MSEL / 32, 256, 0, stream>>>(xf, x, sel, wp, b0, b1, b2, up, out);
        merge_out<<<4096, 256, 0, stream>>>((const float2*)x, (const unsigned int*)up,
                                            head, nxt, (float2*)out);
    } else {
        copy_x<<<4096, 256, 0, stream>>>((const float4*)x, (float4*)out, NROWS * FDIM / 4);
        mlp_compute<false><<<MSEL / 32, 256, 0, stream>>>(xf, x, sel, wp, b0, b1, b2, up, out);
    }
}

// Round 15
// 151.132 us; speedup vs baseline: 1.1610x; 1.0058x over previous
//
#include <hip/hip_runtime.h>
#include <hip/hip_bf16.h>

#define NROWS 400000
#define MSEL  100000
#define FDIM  128

typedef __attribute__((ext_vector_type(8))) short short8;
typedef __attribute__((ext_vector_type(4))) float f32x4;
typedef __attribute__((ext_vector_type(2))) unsigned int uint2v;

__device__ __forceinline__ unsigned short f2bf(float f) {
    unsigned int u = __float_as_uint(f);
    unsigned int r = (u + 0x7fffu + ((u >> 16) & 1u)) >> 16;
    return (unsigned short)r;
}

__device__ __forceinline__ unsigned int pk2bf(float a, float b) {
    __hip_bfloat162 h = __float22bfloat162_rn(make_float2(a, b));
    return *(unsigned int*)&h;
}

__device__ __forceinline__ float elu(float v) {
    return v > 0.f ? v : (__expf(v) - 1.f);
}

// ---------------------------------------------------------------------------
// prep (one kernel, 3 block roles; head[] pre-initialized to -1 by memset):
//   bid <  512          : repack W0/W1/W2 f32 -> bf16 B-fragment order
//   512 <= bid < 903    : build inverted index next[j]=atomicExch(head+sel[j],j)
//   bid >= 903 (12500)  : gather x[sel[j]] -> bf16 A-FRAGMENT order into xf
// Fragment orders verified in R13: B tile (kt,nt)=32x16, lane l holds 8
// contiguous bf16; A frag group (j>>4), lane=(j&15)+((k>>3)&3)*16.
// ---------------------------------------------------------------------------
__global__ void prep(const float* __restrict__ W0, const float* __restrict__ W1,
                     const float* __restrict__ W2, short* __restrict__ wp,
                     const int* __restrict__ sel, const float* __restrict__ x,
                     int* __restrict__ head, int* __restrict__ next,
                     unsigned int* __restrict__ xf32) {
    int bid = blockIdx.x;
    if (bid < 512) {
        int e = bid * 256 + threadIdx.x;         // < 131072
        const float* W; int N; int base; int le;
        if (e < 32768)       { W = W0; N = 256; base = 0;     le = e; }
        else if (e < 98304)  { W = W1; N = 256; base = 32768; le = e - 32768; }
        else                 { W = W2; N = 128; base = 98304; le = e - 98304; }
        int t    = le >> 9;
        int r    = le & 511;
        int lane = r >> 3;
        int j    = r & 7;
        int ntiles = N >> 4;
        int kt = t / ntiles, nt = t % ntiles;
        int k = kt * 32 + (lane >> 4) * 8 + j;
        int n = nt * 16 + (lane & 15);
        wp[base + le] = (short)f2bf(W[k * N + n]);
    } else if (bid < 903) {
        int j = (bid - 512) * 256 + threadIdx.x;
        if (j < MSEL) next[j] = atomicExch(head + sel[j], j);
    } else {
        int g = (bid - 903) * 256 + threadIdx.x;   // < 3,200,000 exactly
        int j = g >> 5, seg = g & 31;
        float4 v = ((const float4*)x)[(size_t)sel[j] * 32 + seg];
        int k0 = seg * 4;
        int lane = (j & 15) + ((k0 >> 3) & 3) * 16;
        int e = k0 & 7;
        int idx = ((((j >> 4) * 4 + (k0 >> 5)) * 512 + lane * 8 + e) >> 1);
        xf32[idx]     = pk2bf(v.x, v.y);
        xf32[idx + 1] = pk2bf(v.z, v.w);
    }
}

__global__ void copy_x(const float4* __restrict__ x, float4* __restrict__ out, int n4) {
    int i = blockIdx.x * blockDim.x + threadIdx.x;
    int stride = gridDim.x * blockDim.x;
    for (; i < n4; i += stride) out[i] = x[i];
}

// ---------------------------------------------------------------------------
// 3-layer ELU MLP (bf16 MFMA).  Block = 512 thr = 8 waves, 64 selected rows
// (halves per-block weight L2 traffic 800->400 MB vs the 32-row structure).
// Wave owns a 32-col slice (16-col for layer 2) -> single L1 pass, B-frags
// register-resident.  K-halved B loads + 2-deep A prefetch bound live VGPR.
// LDS 64KB: h0 [0,16384) shorts, h1 [16384,32768).  up staged at [0,8192)
// after layer 2 (h0 dead): 64 rows x 128 bf16 = 1024 short8 -> one burst
// of 2 x 512 threads (R14 BUG: wrote 2048 short8 at stride 2048 — double
// stride+count, tiles landed on neighbors' regions; fixed to 1024/1024).
// XOR swizzle shortIdx ^= (row&7)<<3 breaks ds_read_b128 bank conflicts.
// Grid 1563: last block has 32 valid rows; frag reads clamped, burst
// guarded by gg < MSEL*16 (= exactly rows < MSEL).
// ---------------------------------------------------------------------------
template <bool SPLIT>
__global__ __launch_bounds__(512) void mlp_compute(
    const short* __restrict__ xf,
    const float* __restrict__ x, const int* __restrict__ sel,
    const short* __restrict__ wp,
    const float* __restrict__ b0v, const float* __restrict__ b1v,
    const float* __restrict__ b2v,
    unsigned short* __restrict__ upOut, float* __restrict__ out) {
    __shared__ __align__(16) short lds[32768];

    const int tid  = threadIdx.x;
    const int lane = tid & 63;
    const int w    = tid >> 6;          // 0..7
    const int rowBase = blockIdx.x * 64;
    const int lm = lane & 15;
    const int kq = lane >> 4;
    const int sxz = (lm & 7) << 3;

    const short* W0p = wp;
    const short* W1p = wp + 32768;
    const short* W2p = wp + 98304;

    const f32x4 zero4 = {0.f, 0.f, 0.f, 0.f};

    // ---- A0 prefetch (2-deep) from frag-ordered xf; clamp for tail block ----
    short8 aA[4], aB[4];
    const int g0 = blockIdx.x * 4;      // 16-row group index of rt=0
#define A0LD(dst, rt) { int rg_ = g0 + (rt); if (rg_ > MSEL/16 - 1) rg_ = MSEL/16 - 1; \
    _Pragma("unroll") for (int kt_ = 0; kt_ < 4; kt_++) \
        dst[kt_] = *(const short8*)(xf + ((size_t)rg_ * 4 + kt_) * 512 + lane * 8); }
    if constexpr (SPLIT) { A0LD(aA, 0); A0LD(aB, 1); }

    // ---- B0 fragments (wave cols = (w*2+ntl)*16 ..) ----
    short8 B0[4][2];
    #pragma unroll
    for (int kt = 0; kt < 4; kt++)
        #pragma unroll
        for (int ntl = 0; ntl < 2; ntl++)
            B0[kt][ntl] = *(const short8*)(W0p + ((kt * 16 + (w * 2 + ntl)) * 512 + lane * 8));

    if constexpr (!SPLIT) {
        // fallback: inline gather 64 rows into h1 region [16384,24576)
        const float4* xv = (const float4*)x;
        #pragma unroll
        for (int it = 0; it < 4; it++) {
            int i = it * 512 + tid;
            int row = i >> 5, seg = i & 31;
            int j = rowBase + row; if (j >= MSEL) j = rowBase;
            float4 v = xv[(size_t)sel[j] * 32 + seg];
            uint2v p = { pk2bf(v.x, v.y), pk2bf(v.z, v.w) };
            *(uint2v*)(&lds[16384 + ((row * 128 + seg * 4) ^ ((row & 7) << 3))]) = p;
        }
        __syncthreads();
    }

    // ===== layer 0: (64x128) @ W0(128x256) =====
    f32x4 acc0[4][2];
    #pragma unroll
    for (int i = 0; i < 4; i++) { acc0[i][0] = zero4; acc0[i][1] = zero4; }

#define L0T(rt, ab) { _Pragma("unroll") for (int ntl_ = 0; ntl_ < 2; ntl_++) \
    _Pragma("unroll") for (int kt_ = 0; kt_ < 4; kt_++) \
        acc0[rt][ntl_] = __builtin_amdgcn_mfma_f32_16x16x32_bf16(ab[kt_], B0[kt_][ntl_], acc0[rt][ntl_], 0, 0, 0); }
#define L0TL(rt) { short8 a_[4]; int rowA_ = (rt) * 16 + lm; \
    _Pragma("unroll") for (int kt_ = 0; kt_ < 4; kt_++) \
        a_[kt_] = *(const short8*)(&lds[16384 + ((rowA_ * 128 + kt_ * 32 + kq * 8) ^ sxz)]); \
    _Pragma("unroll") for (int ntl_ = 0; ntl_ < 2; ntl_++) \
    _Pragma("unroll") for (int kt_ = 0; kt_ < 4; kt_++) \
        acc0[rt][ntl_] = __builtin_amdgcn_mfma_f32_16x16x32_bf16(a_[kt_], B0[kt_][ntl_], acc0[rt][ntl_], 0, 0, 0); }

    if constexpr (SPLIT) {
        L0T(0, aA); A0LD(aA, 2);
        L0T(1, aB); A0LD(aB, 3);
        L0T(2, aA);
        L0T(3, aB);
    } else {
        L0TL(0); L0TL(1); L0TL(2); L0TL(3);
    }

    // epilogue 0 -> h0 [0,16384)
    #pragma unroll
    for (int ntl = 0; ntl < 2; ntl++) {
        int col = (w * 2 + ntl) * 16 + lm;
        float bias = b0v[col];
        #pragma unroll
        for (int rt = 0; rt < 4; rt++) {
            float v0 = elu(acc0[rt][ntl][0] + bias);
            float v1 = elu(acc0[rt][ntl][1] + bias);
            float v2 = elu(acc0[rt][ntl][2] + bias);
            float v3 = elu(acc0[rt][ntl][3] + bias);
            unsigned int u01 = pk2bf(v0, v1), u23 = pk2bf(v2, v3);
            int row = rt * 16 + kq * 4;
            lds[(((row+0) * 256 + col) ^ (((row+0) & 7) << 3))] = (short)(u01 & 0xffff);
            lds[(((row+1) * 256 + col) ^ (((row+1) & 7) << 3))] = (short)(u01 >> 16);
            lds[(((row+2) * 256 + col) ^ (((row+2) & 7) << 3))] = (short)(u23 & 0xffff);
            lds[(((row+3) * 256 + col) ^ (((row+3) & 7) << 3))] = (short)(u23 >> 16);
        }
    }
    __syncthreads();   // bar1

    // ===== layer 1: (64x256) @ W1(256x256), single col-pass, K in 2 halves =====
    f32x4 acc1[4][2];
    #pragma unroll
    for (int i = 0; i < 4; i++) { acc1[i][0] = zero4; acc1[i][1] = zero4; }
    #pragma unroll
    for (int kh = 0; kh < 2; kh++) {
        short8 Bh[4][2];
        #pragma unroll
        for (int kk = 0; kk < 4; kk++)
            #pragma unroll
            for (int ntl = 0; ntl < 2; ntl++)
                Bh[kk][ntl] = *(const short8*)(W1p + (((kh * 4 + kk) * 16 + (w * 2 + ntl)) * 512 + lane * 8));
        #pragma unroll
        for (int rt = 0; rt < 4; rt++) {
            short8 a[4];
            int rowA = rt * 16 + lm;
            #pragma unroll
            for (int kk = 0; kk < 4; kk++)
                a[kk] = *(const short8*)(&lds[(rowA * 256 + (kh * 4 + kk) * 32 + kq * 8) ^ sxz]);
            #pragma unroll
            for (int ntl = 0; ntl < 2; ntl++)
                #pragma unroll
                for (int kk = 0; kk < 4; kk++)
                    acc1[rt][ntl] = __builtin_amdgcn_mfma_f32_16x16x32_bf16(a[kk], Bh[kk][ntl], acc1[rt][ntl], 0, 0, 0);
        }
    }
    // epilogue 1 -> h1 [16384,32768)
    #pragma unroll
    for (int ntl = 0; ntl < 2; ntl++) {
        int col = (w * 2 + ntl) * 16 + lm;
        float bias = b1v[col];
        #pragma unroll
        for (int rt = 0; rt < 4; rt++) {
            float v0 = elu(acc1[rt][ntl][0] + bias);
            float v1 = elu(acc1[rt][ntl][1] + bias);
            float v2 = elu(acc1[rt][ntl][2] + bias);
            float v3 = elu(acc1[rt][ntl][3] + bias);
            unsigned int u01 = pk2bf(v0, v1), u23 = pk2bf(v2, v3);
            int row = rt * 16 + kq * 4;
            lds[16384 + (((row+0) * 256 + col) ^ (((row+0) & 7) << 3))] = (short)(u01 & 0xffff);
            lds[16384 + (((row+1) * 256 + col) ^ (((row+1) & 7) << 3))] = (short)(u01 >> 16);
            lds[16384 + (((row+2) * 256 + col) ^ (((row+2) & 7) << 3))] = (short)(u23 & 0xffff);
            lds[16384 + (((row+3) * 256 + col) ^ (((row+3) & 7) << 3))] = (short)(u23 >> 16);
        }
    }
    __syncthreads();   // bar2

    // ===== layer 2: (64x256) @ W2(256x128), wave col slice = 16 (nt = w) =====
    f32x4 acc2[4];
    #pragma unroll
    for (int i = 0; i < 4; i++) acc2[i] = zero4;
    #pragma unroll
    for (int kh = 0; kh < 2; kh++) {
        short8 Bh[4];
        #pragma unroll
        for (int kk = 0; kk < 4; kk++)
            Bh[kk] = *(const short8*)(W2p + (((kh * 4 + kk) * 8 + w) * 512 + lane * 8));
        #pragma unroll
        for (int rt = 0; rt < 4; rt++) {
            short8 a[4];
            int rowA = rt * 16 + lm;
            #pragma unroll
            for (int kk = 0; kk < 4; kk++)
                a[kk] = *(const short8*)(&lds[16384 + ((rowA * 256 + (kh * 4 + kk) * 32 + kq * 8) ^ sxz)]);
            #pragma unroll
            for (int kk = 0; kk < 4; kk++)
                acc2[rt] = __builtin_amdgcn_mfma_f32_16x16x32_bf16(a[kk], Bh[kk], acc2[rt], 0, 0, 0);
        }
    }
    // epilogue 2: bias+ELU -> stage up tile linear at [0,8192) (h0 dead)
    {
        int col = w * 16 + lm;
        float bias = b2v[col];
        #pragma unroll
        for (int rt = 0; rt < 4; rt++)
            #pragma unroll
            for (int r = 0; r < 4; r++) {
                int row = rt * 16 + kq * 4 + r;
                float v = elu(acc2[rt][r] + bias);
                if (SPLIT) {
                    lds[row * 128 + col] = (short)f2bf(v);
                } else {
                    int j = rowBase + row;
                    if (j < MSEL) atomicAdd(out + (size_t)sel[j] * 128 + col, v);
                }
            }
    }
    if (SPLIT) {
        __syncthreads();   // bar3
        // coalesced up burst: 64 rows x 128 bf16 = 1024 short8, 2 per thread
        const short8* s8 = (const short8*)(&lds[0]);
        short8* u8 = (short8*)upOut;
        #pragma unroll
        for (int i = 0; i < 2; i++) {
            int idx = i * 512 + tid;
            int gg = blockIdx.x * 1024 + idx;
            if (gg < MSEL * 16) u8[gg] = s8[idx];
        }
    }
#undef A0LD
#undef L0T
#undef L0TL
}

// ---------------------------------------------------------------------------
// merge: wave per row, no atomics, no barriers (streaming at full BW).
// head==-1 -> out[r]=x[r]; else out[r] = x[r] + sum_{chain} up[j].
// ---------------------------------------------------------------------------
__global__ __launch_bounds__(256) void merge_out(
    const float2* __restrict__ x2, const unsigned int* __restrict__ up32,
    const int* __restrict__ head, const int* __restrict__ next,
    float2* __restrict__ out2) {
    int wid  = blockIdx.x * 4 + (threadIdx.x >> 6);
    int lane = threadIdx.x & 63;
    int wstride = gridDim.x * 4;
    for (int row = wid; row < NROWS; row += wstride) {
        float2 v = x2[(size_t)row * 64 + lane];
        int j = head[row];
        while (j >= 0) {
            unsigned int u = up32[(size_t)j * 64 + lane];
            v.x += __uint_as_float(u << 16);
            v.y += __uint_as_float(u & 0xffff0000u);
            j = next[j];
        }
        out2[(size_t)row * 64 + lane] = v;
    }
}

extern "C" void kernel_launch(void* const* d_in, const int* in_sizes, int n_in,
                              void* d_out, int out_size, void* d_ws, size_t ws_size,
                              hipStream_t stream) {
    const float* x   = (const float*)d_in[0];
    const int*   sel = (const int*)d_in[1];
    const float* W0  = (const float*)d_in[2];
    const float* b0  = (const float*)d_in[3];
    const float* W1  = (const float*)d_in[4];
    const float* b1  = (const float*)d_in[5];
    const float* W2  = (const float*)d_in[6];
    const float* b2  = (const float*)d_in[7];
    float* out = (float*)d_out;

    char* wsb = (char*)d_ws;
    short* wp          = (short*)wsb;                                   // 0.26 MB
    short* xf          = (short*)(wsb + 262144);                        // 25.6 MB
    unsigned short* up = (unsigned short*)(wsb + 262144 + 25600000);    // 25.6 MB
    int* head          = (int*)(wsb + 262144 + 51200000);               // 1.6 MB
    int* nxt           = head + NROWS;                                  // 0.4 MB
    const size_t need  = 262144 + 51200000 + (size_t)NROWS * 4 + (size_t)MSEL * 4;

    if (ws_size >= need) {
        hipMemsetAsync(head, 0xFF, (size_t)NROWS * 4, stream);          // head[]=-1
        // 512 weight blocks + 391 link blocks + 12500 gather blocks
        prep<<<13403, 256, 0, stream>>>(W0, W1, W2, wp, sel, x, head, nxt,
                                        (unsigned int*)xf);
        mlp_compute<true><<<(MSEL + 63) / 64, 512, 0, stream>>>(
            xf, x, sel, wp, b0, b1, b2, up, out);
        merge_out<<<4096, 256, 0, stream>>>((const float2*)x, (const unsigned int*)up,
                                            head, nxt, (float2*)out);
    } else {
        prep<<<512, 256, 0, stream>>>(W0, W1, W2, wp, sel, x, head, nxt,
                                      (unsigned int*)xf);               // weights only
        copy_x<<<4096, 256, 0, stream>>>((const float4*)x, (float4*)out, NROWS * FDIM / 4);
        mlp_compute<false><<<(MSEL + 63) / 64, 512, 0, stream>>>(
            xf, x, sel, wp, b0, b1, b2, up, out);
    }
}

// Round 17
// 141.997 us; speedup vs baseline: 1.2357x; 1.0643x over previous
//
#include <hip/hip_runtime.h>
#include <hip/hip_bf16.h>

#define NROWS 400000
#define MSEL  100000
#define FDIM  128

typedef __attribute__((ext_vector_type(8))) short short8;
typedef __attribute__((ext_vector_type(4))) float f32x4;
typedef __attribute__((ext_vector_type(2))) float f32x2;
typedef __attribute__((ext_vector_type(2))) unsigned int uint2v;

__device__ __forceinline__ unsigned short f2bf(float f) {
    unsigned int u = __float_as_uint(f);
    unsigned int r = (u + 0x7fffu + ((u >> 16) & 1u)) >> 16;
    return (unsigned short)r;
}

__device__ __forceinline__ unsigned int pk2bf(float a, float b) {
    __hip_bfloat162 h = __float22bfloat162_rn(make_float2(a, b));
    return *(unsigned int*)&h;
}

__device__ __forceinline__ float elu(float v) {
    return v > 0.f ? v : (__expf(v) - 1.f);
}

// ---------------------------------------------------------------------------
// prep (one kernel, 3 block roles; head[] pre-initialized to -1 by memset):
//   bid <  512          : repack W0/W1/W2 f32 -> bf16 B-fragment order
//   512 <= bid < 903    : build inverted index next[j]=atomicExch(head+sel[j],j)
//   bid >= 903 (12500)  : gather x[sel[j]] -> bf16 A-FRAGMENT order into xf
// Fragment orders verified in R13: B tile (kt,nt)=32x16, lane l holds 8
// contiguous bf16; A frag group (j>>4), lane=(j&15)+((k>>3)&3)*16.
// ---------------------------------------------------------------------------
__global__ void prep(const float* __restrict__ W0, const float* __restrict__ W1,
                     const float* __restrict__ W2, short* __restrict__ wp,
                     const int* __restrict__ sel, const float* __restrict__ x,
                     int* __restrict__ head, int* __restrict__ next,
                     unsigned int* __restrict__ xf32) {
    int bid = blockIdx.x;
    if (bid < 512) {
        int e = bid * 256 + threadIdx.x;         // < 131072
        const float* W; int N; int base; int le;
        if (e < 32768)       { W = W0; N = 256; base = 0;     le = e; }
        else if (e < 98304)  { W = W1; N = 256; base = 32768; le = e - 32768; }
        else                 { W = W2; N = 128; base = 98304; le = e - 98304; }
        int t    = le >> 9;
        int r    = le & 511;
        int lane = r >> 3;
        int j    = r & 7;
        int ntiles = N >> 4;
        int kt = t / ntiles, nt = t % ntiles;
        int k = kt * 32 + (lane >> 4) * 8 + j;
        int n = nt * 16 + (lane & 15);
        wp[base + le] = (short)f2bf(W[k * N + n]);
    } else if (bid < 903) {
        int j = (bid - 512) * 256 + threadIdx.x;
        if (j < MSEL) next[j] = atomicExch(head + sel[j], j);
    } else {
        int g = (bid - 903) * 256 + threadIdx.x;   // < 3,200,000 exactly
        int j = g >> 5, seg = g & 31;
        float4 v = ((const float4*)x)[(size_t)sel[j] * 32 + seg];
        int k0 = seg * 4;
        int lane = (j & 15) + ((k0 >> 3) & 3) * 16;
        int e = k0 & 7;
        int idx = ((((j >> 4) * 4 + (k0 >> 5)) * 512 + lane * 8 + e) >> 1);
        xf32[idx]     = pk2bf(v.x, v.y);
        xf32[idx + 1] = pk2bf(v.z, v.w);
    }
}

__global__ void copy_x(const float4* __restrict__ x, float4* __restrict__ out, int n4) {
    int i = blockIdx.x * blockDim.x + threadIdx.x;
    int stride = gridDim.x * blockDim.x;
    for (; i < n4; i += stride) out[i] = x[i];
}

// ---------------------------------------------------------------------------
// 3-layer ELU MLP (bf16 MFMA).  Block = 512 thr = 8 waves, 64 selected rows.
// Wave owns a 32-col slice (16-col for layer 2) -> single L1 pass, B-frags
// register-resident.  K-halved B loads + 2-deep A prefetch bound live VGPR.
// LDS 64KB: h0 [0,16384) shorts, h1 [16384,32768).  up staged at [0,8192)
// after layer 2 (h0 dead): 64 rows x 128 bf16 = 1024 short8, 2/thread.
// XOR swizzle shortIdx ^= (row&7)<<3 breaks ds_read_b128 bank conflicts.
// Grid 1563: last block has 32 valid rows; frag reads clamped, burst
// guarded by gg < MSEL*16.
// ---------------------------------------------------------------------------
template <bool SPLIT>
__global__ __launch_bounds__(512) void mlp_compute(
    const short* __restrict__ xf,
    const float* __restrict__ x, const int* __restrict__ sel,
    const short* __restrict__ wp,
    const float* __restrict__ b0v, const float* __restrict__ b1v,
    const float* __restrict__ b2v,
    unsigned short* __restrict__ upOut, float* __restrict__ out) {
    __shared__ __align__(16) short lds[32768];

    const int tid  = threadIdx.x;
    const int lane = tid & 63;
    const int w    = tid >> 6;          // 0..7
    const int rowBase = blockIdx.x * 64;
    const int lm = lane & 15;
    const int kq = lane >> 4;
    const int sxz = (lm & 7) << 3;

    const short* W0p = wp;
    const short* W1p = wp + 32768;
    const short* W2p = wp + 98304;

    const f32x4 zero4 = {0.f, 0.f, 0.f, 0.f};

    // ---- A0 prefetch (2-deep) from frag-ordered xf; clamp for tail block ----
    short8 aA[4], aB[4];
    const int g0 = blockIdx.x * 4;      // 16-row group index of rt=0
#define A0LD(dst, rt) { int rg_ = g0 + (rt); if (rg_ > MSEL/16 - 1) rg_ = MSEL/16 - 1; \
    _Pragma("unroll") for (int kt_ = 0; kt_ < 4; kt_++) \
        dst[kt_] = *(const short8*)(xf + ((size_t)rg_ * 4 + kt_) * 512 + lane * 8); }
    if constexpr (SPLIT) { A0LD(aA, 0); A0LD(aB, 1); }

    // ---- B0 fragments (wave cols = (w*2+ntl)*16 ..) ----
    short8 B0[4][2];
    #pragma unroll
    for (int kt = 0; kt < 4; kt++)
        #pragma unroll
        for (int ntl = 0; ntl < 2; ntl++)
            B0[kt][ntl] = *(const short8*)(W0p + ((kt * 16 + (w * 2 + ntl)) * 512 + lane * 8));

    if constexpr (!SPLIT) {
        // fallback: inline gather 64 rows into h1 region [16384,24576)
        const float4* xv = (const float4*)x;
        #pragma unroll
        for (int it = 0; it < 4; it++) {
            int i = it * 512 + tid;
            int row = i >> 5, seg = i & 31;
            int j = rowBase + row; if (j >= MSEL) j = rowBase;
            float4 v = xv[(size_t)sel[j] * 32 + seg];
            uint2v p = { pk2bf(v.x, v.y), pk2bf(v.z, v.w) };
            *(uint2v*)(&lds[16384 + ((row * 128 + seg * 4) ^ ((row & 7) << 3))]) = p;
        }
        __syncthreads();
    }

    // ===== layer 0: (64x128) @ W0(128x256) =====
    f32x4 acc0[4][2];
    #pragma unroll
    for (int i = 0; i < 4; i++) { acc0[i][0] = zero4; acc0[i][1] = zero4; }

#define L0T(rt, ab) { _Pragma("unroll") for (int ntl_ = 0; ntl_ < 2; ntl_++) \
    _Pragma("unroll") for (int kt_ = 0; kt_ < 4; kt_++) \
        acc0[rt][ntl_] = __builtin_amdgcn_mfma_f32_16x16x32_bf16(ab[kt_], B0[kt_][ntl_], acc0[rt][ntl_], 0, 0, 0); }
#define L0TL(rt) { short8 a_[4]; int rowA_ = (rt) * 16 + lm; \
    _Pragma("unroll") for (int kt_ = 0; kt_ < 4; kt_++) \
        a_[kt_] = *(const short8*)(&lds[16384 + ((rowA_ * 128 + kt_ * 32 + kq * 8) ^ sxz)]); \
    _Pragma("unroll") for (int ntl_ = 0; ntl_ < 2; ntl_++) \
    _Pragma("unroll") for (int kt_ = 0; kt_ < 4; kt_++) \
        acc0[rt][ntl_] = __builtin_amdgcn_mfma_f32_16x16x32_bf16(a_[kt_], B0[kt_][ntl_], acc0[rt][ntl_], 0, 0, 0); }

    if constexpr (SPLIT) {
        L0T(0, aA); A0LD(aA, 2);
        L0T(1, aB); A0LD(aB, 3);
        L0T(2, aA);
        L0T(3, aB);
    } else {
        L0TL(0); L0TL(1); L0TL(2); L0TL(3);
    }

    // epilogue 0 -> h0 [0,16384)
    #pragma unroll
    for (int ntl = 0; ntl < 2; ntl++) {
        int col = (w * 2 + ntl) * 16 + lm;
        float bias = b0v[col];
        #pragma unroll
        for (int rt = 0; rt < 4; rt++) {
            float v0 = elu(acc0[rt][ntl][0] + bias);
            float v1 = elu(acc0[rt][ntl][1] + bias);
            float v2 = elu(acc0[rt][ntl][2] + bias);
            float v3 = elu(acc0[rt][ntl][3] + bias);
            unsigned int u01 = pk2bf(v0, v1), u23 = pk2bf(v2, v3);
            int row = rt * 16 + kq * 4;
            lds[(((row+0) * 256 + col) ^ (((row+0) & 7) << 3))] = (short)(u01 & 0xffff);
            lds[(((row+1) * 256 + col) ^ (((row+1) & 7) << 3))] = (short)(u01 >> 16);
            lds[(((row+2) * 256 + col) ^ (((row+2) & 7) << 3))] = (short)(u23 & 0xffff);
            lds[(((row+3) * 256 + col) ^ (((row+3) & 7) << 3))] = (short)(u23 >> 16);
        }
    }
    __syncthreads();   // bar1

    // ===== layer 1: (64x256) @ W1(256x256), single col-pass, K in 2 halves =====
    f32x4 acc1[4][2];
    #pragma unroll
    for (int i = 0; i < 4; i++) { acc1[i][0] = zero4; acc1[i][1] = zero4; }
    #pragma unroll
    for (int kh = 0; kh < 2; kh++) {
        short8 Bh[4][2];
        #pragma unroll
        for (int kk = 0; kk < 4; kk++)
            #pragma unroll
            for (int ntl = 0; ntl < 2; ntl++)
                Bh[kk][ntl] = *(const short8*)(W1p + (((kh * 4 + kk) * 16 + (w * 2 + ntl)) * 512 + lane * 8));
        #pragma unroll
        for (int rt = 0; rt < 4; rt++) {
            short8 a[4];
            int rowA = rt * 16 + lm;
            #pragma unroll
            for (int kk = 0; kk < 4; kk++)
                a[kk] = *(const short8*)(&lds[(rowA * 256 + (kh * 4 + kk) * 32 + kq * 8) ^ sxz]);
            #pragma unroll
            for (int ntl = 0; ntl < 2; ntl++)
                #pragma unroll
                for (int kk = 0; kk < 4; kk++)
                    acc1[rt][ntl] = __builtin_amdgcn_mfma_f32_16x16x32_bf16(a[kk], Bh[kk][ntl], acc1[rt][ntl], 0, 0, 0);
        }
    }
    // epilogue 1 -> h1 [16384,32768)
    #pragma unroll
    for (int ntl = 0; ntl < 2; ntl++) {
        int col = (w * 2 + ntl) * 16 + lm;
        float bias = b1v[col];
        #pragma unroll
        for (int rt = 0; rt < 4; rt++) {
            float v0 = elu(acc1[rt][ntl][0] + bias);
            float v1 = elu(acc1[rt][ntl][1] + bias);
            float v2 = elu(acc1[rt][ntl][2] + bias);
            float v3 = elu(acc1[rt][ntl][3] + bias);
            unsigned int u01 = pk2bf(v0, v1), u23 = pk2bf(v2, v3);
            int row = rt * 16 + kq * 4;
            lds[16384 + (((row+0) * 256 + col) ^ (((row+0) & 7) << 3))] = (short)(u01 & 0xffff);
            lds[16384 + (((row+1) * 256 + col) ^ (((row+1) & 7) << 3))] = (short)(u01 >> 16);
            lds[16384 + (((row+2) * 256 + col) ^ (((row+2) & 7) << 3))] = (short)(u23 & 0xffff);
            lds[16384 + (((row+3) * 256 + col) ^ (((row+3) & 7) << 3))] = (short)(u23 >> 16);
        }
    }
    __syncthreads();   // bar2

    // ===== layer 2: (64x256) @ W2(256x128), wave col slice = 16 (nt = w) =====
    f32x4 acc2[4];
    #pragma unroll
    for (int i = 0; i < 4; i++) acc2[i] = zero4;
    #pragma unroll
    for (int kh = 0; kh < 2; kh++) {
        short8 Bh[4];
        #pragma unroll
        for (int kk = 0; kk < 4; kk++)
            Bh[kk] = *(const short8*)(W2p + (((kh * 4 + kk) * 8 + w) * 512 + lane * 8));
        #pragma unroll
        for (int rt = 0; rt < 4; rt++) {
            short8 a[4];
            int rowA = rt * 16 + lm;
            #pragma unroll
            for (int kk = 0; kk < 4; kk++)
                a[kk] = *(const short8*)(&lds[16384 + ((rowA * 256 + (kh * 4 + kk) * 32 + kq * 8) ^ sxz)]);
            #pragma unroll
            for (int kk = 0; kk < 4; kk++)
                acc2[rt] = __builtin_amdgcn_mfma_f32_16x16x32_bf16(a[kk], Bh[kk], acc2[rt], 0, 0, 0);
        }
    }
    // epilogue 2: bias+ELU -> stage up tile linear at [0,8192) (h0 dead)
    {
        int col = w * 16 + lm;
        float bias = b2v[col];
        #pragma unroll
        for (int rt = 0; rt < 4; rt++)
            #pragma unroll
            for (int r = 0; r < 4; r++) {
                int row = rt * 16 + kq * 4 + r;
                float v = elu(acc2[rt][r] + bias);
                if (SPLIT) {
                    lds[row * 128 + col] = (short)f2bf(v);
                } else {
                    int j = rowBase + row;
                    if (j < MSEL) atomicAdd(out + (size_t)sel[j] * 128 + col, v);
                }
            }
    }
    if (SPLIT) {
        __syncthreads();   // bar3
        // coalesced up burst: 64 rows x 128 bf16 = 1024 short8, 2 per thread
        const short8* s8 = (const short8*)(&lds[0]);
        short8* u8 = (short8*)upOut;
        #pragma unroll
        for (int i = 0; i < 2; i++) {
            int idx = i * 512 + tid;
            int gg = blockIdx.x * 1024 + idx;
            if (gg < MSEL * 16) u8[gg] = s8[idx];
        }
    }
#undef A0LD
#undef L0T
#undef L0TL
}

// ---------------------------------------------------------------------------
// merge: wave per row, no atomics, no barriers.  R17 (=R16 fixed):
//  - 8192 blocks (2x waves -> deeper TLP over the head->up dependent chain)
//  - head[] prefetched one row-iteration ahead (hides chain-head latency)
//  - nontemporal stores for out via clang ext-vector f32x2 (bypass L2/L3
//    write-allocate; __builtin_nontemporal_store rejects HIP_vector_type)
// head==-1 -> out[r]=x[r]; else out[r] = x[r] + sum_{chain} up[j].
// ---------------------------------------------------------------------------
__global__ __launch_bounds__(256) void merge_out(
    const f32x2* __restrict__ x2, const unsigned int* __restrict__ up32,
    const int* __restrict__ head, const int* __restrict__ next,
    f32x2* __restrict__ out2) {
    int wid  = blockIdx.x * 4 + (threadIdx.x >> 6);
    int lane = threadIdx.x & 63;
    int wstride = gridDim.x * 4;
    int row = wid;
    if (row >= NROWS) return;
    int hd = head[row];
    for (; row < NROWS; row += wstride) {
        int nrow = row + wstride;
        int nhd = (nrow < NROWS) ? head[nrow] : -1;   // prefetch next head
        f32x2 v = x2[(size_t)row * 64 + lane];
        int j = hd;
        while (j >= 0) {
            unsigned int u = up32[(size_t)j * 64 + lane];
            v.x += __uint_as_float(u << 16);
            v.y += __uint_as_float(u & 0xffff0000u);
            j = next[j];
        }
        __builtin_nontemporal_store(v, &out2[(size_t)row * 64 + lane]);
        hd = nhd;
    }
}

extern "C" void kernel_launch(void* const* d_in, const int* in_sizes, int n_in,
                              void* d_out, int out_size, void* d_ws, size_t ws_size,
                              hipStream_t stream) {
    const float* x   = (const float*)d_in[0];
    const int*   sel = (const int*)d_in[1];
    const float* W0  = (const float*)d_in[2];
    const float* b0  = (const float*)d_in[3];
    const float* W1  = (const float*)d_in[4];
    const float* b1  = (const float*)d_in[5];
    const float* W2  = (const float*)d_in[6];
    const float* b2  = (const float*)d_in[7];
    float* out = (float*)d_out;

    char* wsb = (char*)d_ws;
    short* wp          = (short*)wsb;                                   // 0.26 MB
    short* xf          = (short*)(wsb + 262144);                        // 25.6 MB
    unsigned short* up = (unsigned short*)(wsb + 262144 + 25600000);    // 25.6 MB
    int* head          = (int*)(wsb + 262144 + 51200000);               // 1.6 MB
    int* nxt           = head + NROWS;                                  // 0.4 MB
    const size_t need  = 262144 + 51200000 + (size_t)NROWS * 4 + (size_t)MSEL * 4;

    if (ws_size >= need) {
        (void)hipMemsetAsync(head, 0xFF, (size_t)NROWS * 4, stream);    // head[]=-1
        // 512 weight blocks + 391 link blocks + 12500 gather blocks
        prep<<<13403, 256, 0, stream>>>(W0, W1, W2, wp, sel, x, head, nxt,
                                        (unsigned int*)xf);
        mlp_compute<true><<<(MSEL + 63) / 64, 512, 0, stream>>>(
            xf, x, sel, wp, b0, b1, b2, up, out);
        merge_out<<<8192, 256, 0, stream>>>((const f32x2*)x, (const unsigned int*)up,
                                            head, nxt, (f32x2*)out);
    } else {
        prep<<<512, 256, 0, stream>>>(W0, W1, W2, wp, sel, x, head, nxt,
                                      (unsigned int*)xf);               // weights only
        copy_x<<<4096, 256, 0, stream>>>((const float4*)x, (float4*)out, NROWS * FDIM / 4);
        mlp_compute<false><<<(MSEL + 63) / 64, 512, 0, stream>>>(
            xf, x, sel, wp, b0, b1, b2, up, out);
    }
}